// Round 2
// baseline (79.874 us; speedup 1.0000x reference)
//
#include <hip/hip_runtime.h>

// Single fused kernel, redundancy-reduced.
// lse = log(sum(exp(W))) is recomputed per block; with 128 blocks the
// redundant W traffic is 128 x 175 KB = 22 MB (vs 90 MB at 512 blocks, which
// contended with the harness's 256 MB workspace poison-fill thrashing L2).
// No inter-block communication -> safe under undefined dispatch order.
//
// Per block: 64 rows (16 per wave). Each wave issues its 16 x-row loads
// FIRST so their HBM latency hides under the exp(W) loop, then computes the
// block-local lse, then builds 16 ballots; lane r captures ballot r, so
// lanes 0..15 compute the 16 combinatorial ranks in parallel.
// (table = all popcount<=3 64-bit vectors, popcount-major, lexicographic.)
__global__ __launch_bounds__(256) void fused_rank_kernel(
        const int* __restrict__ x,
        const float* __restrict__ W, int T,
        float* __restrict__ out, int batch) {
    __shared__ float red[4];
    __shared__ float s_lse;
    const int tid  = threadIdx.x;
    const int lane = tid & 63;
    const int wave = tid >> 6;

    // ---- issue phase-2 loads early: 16 rows per wave, coalesced ----
    const int wave_row0 = blockIdx.x * 64 + wave * 16;
    int vals[16];
    #pragma unroll
    for (int r = 0; r < 16; ++r) {
        const int row = wave_row0 + r;
        vals[r] = (row < batch) ? x[(size_t)row * 64 + lane] : 0;
    }

    // ---- Phase 1: block-local sum(exp(W)), float4-vectorized ----
    float s = 0.0f;
    const int T4 = T >> 2;
    const float4* __restrict__ W4 = (const float4*)W;
    for (int i = tid; i < T4; i += 256) {
        const float4 v = W4[i];
        s += __expf(v.x) + __expf(v.y) + __expf(v.z) + __expf(v.w);
    }
    for (int i = (T4 << 2) + tid; i < T; i += 256)
        s += __expf(W[i]);
    #pragma unroll
    for (int off = 32; off > 0; off >>= 1) s += __shfl_down(s, off, 64);
    if (lane == 0) red[wave] = s;
    __syncthreads();
    if (tid == 0) s_lse = __logf(red[0] + red[1] + red[2] + red[3]);
    __syncthreads();
    const float lse = s_lse;

    // ---- Phase 2: ballots; lane r keeps row r's mask ----
    unsigned long long mymask = 0ull;
    #pragma unroll
    for (int r = 0; r < 16; ++r) {
        const unsigned long long mk = __ballot(vals[r] != 0);
        if (lane == r) mymask = mk;
    }

    if (lane < 16) {
        const int row = wave_row0 + lane;
        if (row < batch) {
            const int m = __popcll(mymask);
            int idx;
            if (m == 0) {
                idx = 0;
            } else {
                unsigned long long t = mymask;
                const int a = __builtin_ctzll(t); t &= t - 1;
                if (m == 1) {
                    idx = 1 + a;
                } else {
                    const int b = __builtin_ctzll(t); t &= t - 1;
                    if (m == 2) {
                        // 65 + sum_{j<a} C(63-j,1) + (b-a-1)
                        idx = 65 + ((4032 - (63 - a) * (64 - a)) >> 1) + (b - a - 1);
                    } else {
                        const int c = __builtin_ctzll(t);
                        // base 1 + 64 + 2016 = 2081
                        const int s1 = 41664 - ((64 - a) * (63 - a) * (62 - a)) / 6; // sum_{j<a} C(63-j,2)
                        const int s2 = ((62 - a) * (63 - a) - (63 - b) * (64 - b)) >> 1; // sum_{a<j<b} C(63-j,1)
                        idx = 2081 + s1 + s2 + (c - b - 1);
                    }
                }
            }
            out[row] = W[idx] - lse;
        }
    }
}

extern "C" void kernel_launch(void* const* d_in, const int* in_sizes, int n_in,
                              void* d_out, int out_size, void* d_ws, size_t ws_size,
                              hipStream_t stream) {
    const int*   x = (const int*)d_in[0];     // (B, 64) int32
    // d_in[1] = table — unused (structure known in closed form)
    const float* W = (const float*)d_in[2];   // (T,) float32
    float* out     = (float*)d_out;           // (B,) float32
    (void)d_ws; (void)ws_size;                // workspace unused

    const int T = in_sizes[2];                // 43745
    const int B = in_sizes[0] / 64;           // 8192

    const int blocks = (B + 63) / 64;         // 64 rows per block -> 128 blocks
    fused_rank_kernel<<<blocks, 256, 0, stream>>>(x, W, T, out, B);
}